// Round 3
// baseline (1532.799 us; speedup 1.0000x reference)
//
#include <hip/hip_runtime.h>
#include <cstdio>

// Problem dims: B=64, CIN=256, CP=128, H=W=32, N=1024
// stacked conv channels: 384 = theta(128) | phi(128) | gamma(128)
// Attention middle processed in 4 chunks of 16 batch elements (per-batch softmax
// is independent), so the logits buffer is only [16][1024][1024] floats = 64 MB.

static constexpr int BCHUNK = 16;
static constexpr int NCHUNK = 4;

// ---- workspace layout (in floats) ----
static constexpr long OFF_WSTACK = 0;               // 384*256 = 98304
static constexpr long OFF_PARAMS = 98304;           // b(384) g(384) beta(384) = 1152
static constexpr long OFF_STATS1 = 99456;           // 384*2
static constexpr long OFF_STATS2 = 100224;          // 256*2
static constexpr long OFF_PMAX   = 100736;          // 64*128
static constexpr long OFF_BMAX   = 108928;          // 64
static constexpr long OFF_INVZ   = 108992;          // 64
static constexpr long OFF_PZ     = 109056;          // doubles: 64*128 -> 16384 floats
static constexpr long OFF_Y3     = 131072;          // 64*384*1024 = 25165824 (also out0 alias)
static constexpr long OFF_SAT    = OFF_Y3 + 25165824;   // 64*128*1024 = 8388608
static constexpr long OFF_P     = OFF_SAT + 8388608;    // 16*1024*1024 = 16777216
static constexpr long WS_FLOATS = OFF_P + 16777216;     // 50462720 floats = ~202 MB

// ---------------- param stacking ----------------
__global__ void stack_params(const float* tw, const float* tb, const float* tg, const float* tbe,
                             const float* pw, const float* pb, const float* pg, const float* pbe,
                             const float* gw, const float* gb, const float* gg, const float* gbe,
                             float* Wst, float* vecs) {
    int i = blockIdx.x * 256 + threadIdx.x;
    if (i < 98304) {
        int o = i >> 8, c = i & 255;
        float v = (o < 128) ? tw[o * 256 + c] : (o < 256) ? pw[(o - 128) * 256 + c]
                                                          : gw[(o - 256) * 256 + c];
        Wst[i] = v;
    }
    if (i < 384) {
        float b  = (i < 128) ? tb[i]  : (i < 256) ? pb[i - 128]  : gb[i - 256];
        float g  = (i < 128) ? tg[i]  : (i < 256) ? pg[i - 128]  : gg[i - 256];
        float be = (i < 128) ? tbe[i] : (i < 256) ? pbe[i - 128] : gbe[i - 256];
        vecs[i] = b; vecs[384 + i] = g; vecs[768 + i] = be;
    }
}

// ---------------- generic tiled fp32 GEMM ----------------
// C[bz][m,j] = scale[bz] * sum_k A[m,k (or k,m)] * B[bz][k,j] + bias[m]
template <bool A_TRANS>
__global__ __launch_bounds__(256) void gemm_kernel(
    const float* __restrict__ A, long aBatch, int lda,
    const float* __restrict__ B, long bBatch, int ldb,
    float* __restrict__ C, long cBatch, int ldc,
    int K,
    const float* __restrict__ bias,
    const float* __restrict__ batchScale) {
    constexpr int TM = 64, TJ = 64, TK = 16;
    __shared__ float As[TK][TM + 1];
    __shared__ float Bs[TK][TJ + 1];
    const int tid = threadIdx.x;
    const int tx = tid & 15, ty = tid >> 4;
    const float* Ab = A + (long)blockIdx.z * aBatch;
    const float* Bb = B + (long)blockIdx.z * bBatch;
    float* Cb = C + (long)blockIdx.z * cBatch;
    const int m0 = blockIdx.y * TM, j0 = blockIdx.x * TJ;

    float acc[4][4] = {};
    for (int kt = 0; kt < K; kt += TK) {
        if (A_TRANS) {
#pragma unroll
            for (int i = 0; i < 4; ++i) {
                int idx = tid + 256 * i;
                int k = idx / TM, m = idx % TM;
                As[k][m] = Ab[(long)(kt + k) * lda + (m0 + m)];
            }
        } else {
#pragma unroll
            for (int i = 0; i < 4; ++i) {
                int idx = tid + 256 * i;
                int m = idx / TK, k = idx % TK;
                As[k][m] = Ab[(long)(m0 + m) * lda + (kt + k)];
            }
        }
#pragma unroll
        for (int i = 0; i < 4; ++i) {
            int idx = tid + 256 * i;
            int k = idx / TJ, j = idx % TJ;
            Bs[k][j] = Bb[(long)(kt + k) * ldb + (j0 + j)];
        }
        __syncthreads();
#pragma unroll
        for (int k = 0; k < TK; ++k) {
            float a[4], b[4];
#pragma unroll
            for (int i = 0; i < 4; ++i) a[i] = As[k][ty * 4 + i];
#pragma unroll
            for (int j = 0; j < 4; ++j) b[j] = Bs[k][tx * 4 + j];
#pragma unroll
            for (int i = 0; i < 4; ++i)
#pragma unroll
                for (int j = 0; j < 4; ++j) acc[i][j] += a[i] * b[j];
        }
        __syncthreads();
    }
    const float scale = batchScale ? batchScale[blockIdx.z] : 1.0f;
#pragma unroll
    for (int i = 0; i < 4; ++i) {
        const float bi = bias ? bias[m0 + ty * 4 + i] : 0.0f;
#pragma unroll
        for (int j = 0; j < 4; ++j) {
            Cb[(long)(m0 + ty * 4 + i) * ldc + (j0 + tx * 4 + j)] = acc[i][j] * scale + bi;
        }
    }
}

// ---------------- batchnorm stats -> per-channel scale/shift ----------------
__global__ __launch_bounds__(256) void stats_kernel(const float* __restrict__ Y, long bStride,
                                                    const float* __restrict__ g,
                                                    const float* __restrict__ beta,
                                                    float* __restrict__ ss) {
    const int ch = blockIdx.x;
    const int tid = threadIdx.x;
    double s = 0.0, s2 = 0.0;
    for (int b = 0; b < 64; ++b) {
        const float* p = Y + (long)b * bStride + (long)ch * 1024;
        for (int n = tid; n < 1024; n += 256) {
            float v = p[n];
            s += v;
            s2 += (double)v * v;
        }
    }
    __shared__ double ls[256], ls2[256];
    ls[tid] = s; ls2[tid] = s2;
    __syncthreads();
    for (int o = 128; o > 0; o >>= 1) {
        if (tid < o) { ls[tid] += ls[tid + o]; ls2[tid] += ls2[tid + o]; }
        __syncthreads();
    }
    if (tid == 0) {
        double mean = ls[0] / 65536.0;
        double var = ls2[0] / 65536.0 - mean * mean;
        double sc = (double)g[ch] / sqrt(var + 1e-5);
        ss[2 * ch] = (float)sc;
        ss[2 * ch + 1] = (float)((double)beta[ch] - mean * sc);
    }
}

// normalize in place (float4), C channels, each channel holds 1024 floats (=256 float4)
__global__ __launch_bounds__(256) void norm_kernel(float4* __restrict__ Y,
                                                   const float* __restrict__ ss,
                                                   long total4, int C) {
    for (long i = (long)blockIdx.x * 256 + threadIdx.x; i < total4; i += (long)gridDim.x * 256) {
        int ch = (int)((i >> 8) % C);
        float sc = ss[2 * ch], sh = ss[2 * ch + 1];
        float4 v = Y[i];
        v.x = v.x * sc + sh; v.y = v.y * sc + sh; v.z = v.z * sc + sh; v.w = v.w * sc + sh;
        Y[i] = v;
    }
}

// ---------------- softmax pieces (per batch element, chunk-local S) ----------------
__global__ __launch_bounds__(256) void max_kernel(const float* __restrict__ S, float* __restrict__ pmax) {
    const int b = blockIdx.y, blk = blockIdx.x;
    const float* p = S + (long)b * 1048576 + (long)blk * 8192;
    float m = -3.4e38f;
    for (int i = threadIdx.x; i < 8192; i += 256) m = fmaxf(m, p[i]);
    __shared__ float lm[256];
    lm[threadIdx.x] = m;
    __syncthreads();
    for (int o = 128; o > 0; o >>= 1) {
        if (threadIdx.x < o) lm[threadIdx.x] = fmaxf(lm[threadIdx.x], lm[threadIdx.x + o]);
        __syncthreads();
    }
    if (threadIdx.x == 0) pmax[b * 128 + blk] = lm[0];
}

__global__ __launch_bounds__(128) void max_reduce_kernel(const float* __restrict__ pmax,
                                                         float* __restrict__ bmax) {
    const int b = blockIdx.x;
    __shared__ float lm[128];
    lm[threadIdx.x] = pmax[b * 128 + threadIdx.x];
    __syncthreads();
    for (int o = 64; o > 0; o >>= 1) {
        if (threadIdx.x < o) lm[threadIdx.x] = fmaxf(lm[threadIdx.x], lm[threadIdx.x + o]);
        __syncthreads();
    }
    if (threadIdx.x == 0) bmax[b] = lm[0];
}

__global__ __launch_bounds__(256) void expsum_kernel(float* __restrict__ S,
                                                     const float* __restrict__ bmax,
                                                     double* __restrict__ pz) {
    const int b = blockIdx.y, blk = blockIdx.x;
    const float mb = bmax[b];
    float* p = S + (long)b * 1048576 + (long)blk * 8192;
    double s = 0.0;
    for (int i = threadIdx.x; i < 8192; i += 256) {
        float e = expf(p[i] - mb);
        p[i] = e;
        s += e;
    }
    __shared__ double ls[256];
    ls[threadIdx.x] = s;
    __syncthreads();
    for (int o = 128; o > 0; o >>= 1) {
        if (threadIdx.x < o) ls[threadIdx.x] += ls[threadIdx.x + o];
        __syncthreads();
    }
    if (threadIdx.x == 0) pz[b * 128 + blk] = ls[0];
}

__global__ __launch_bounds__(128) void z_reduce_kernel(const double* __restrict__ pz,
                                                       float* __restrict__ invz) {
    const int b = blockIdx.x;
    __shared__ double l[128];
    l[threadIdx.x] = pz[b * 128 + threadIdx.x];
    __syncthreads();
    for (int o = 64; o > 0; o >>= 1) {
        if (threadIdx.x < o) l[threadIdx.x] += l[threadIdx.x + o];
        __syncthreads();
    }
    if (threadIdx.x == 0) invz[b] = (float)(1.0 / l[0]);
}

// out = x + out0*scale[ch] + shift[ch], 256 channels of 1024 (=256 float4)
__global__ __launch_bounds__(256) void final_kernel(const float4* __restrict__ x,
                                                    const float4* __restrict__ out0,
                                                    const float* __restrict__ ss,
                                                    float4* __restrict__ out, long total4) {
    for (long i = (long)blockIdx.x * 256 + threadIdx.x; i < total4; i += (long)gridDim.x * 256) {
        int ch = (int)((i >> 8) & 255);
        float sc = ss[2 * ch], sh = ss[2 * ch + 1];
        float4 a = x[i], v = out0[i];
        v.x = a.x + v.x * sc + sh;
        v.y = a.y + v.y * sc + sh;
        v.z = a.z + v.z * sc + sh;
        v.w = a.w + v.w * sc + sh;
        out[i] = v;
    }
}

extern "C" void kernel_launch(void* const* d_in, const int* in_sizes, int n_in,
                              void* d_out, int out_size, void* d_ws, size_t ws_size,
                              hipStream_t stream) {
    const float* x        = (const float*)d_in[0];
    const float* theta_w  = (const float*)d_in[1];
    const float* theta_b  = (const float*)d_in[2];
    const float* theta_g  = (const float*)d_in[3];
    const float* theta_be = (const float*)d_in[4];
    const float* phi_w    = (const float*)d_in[5];
    const float* phi_b    = (const float*)d_in[6];
    const float* phi_g    = (const float*)d_in[7];
    const float* phi_be   = (const float*)d_in[8];
    const float* gamma_w  = (const float*)d_in[9];
    const float* gamma_b  = (const float*)d_in[10];
    const float* gamma_g  = (const float*)d_in[11];
    const float* gamma_be = (const float*)d_in[12];
    const float* omega_w  = (const float*)d_in[13];
    const float* omega_b  = (const float*)d_in[14];
    const float* omega_g  = (const float*)d_in[15];
    const float* omega_be = (const float*)d_in[16];
    float* out = (float*)d_out;

    const size_t need = (size_t)WS_FLOATS * 4;
    if (ws_size < need) {
        fprintf(stderr, "kernel_launch: ws_size %zu < needed %zu\n", ws_size, need);
        return;
    }
    float* ws = (float*)d_ws;
    float* Wst   = ws + OFF_WSTACK;
    float* vecs  = ws + OFF_PARAMS;   // b | g | beta (384 each)
    float* st1   = ws + OFF_STATS1;
    float* st2   = ws + OFF_STATS2;
    float* pmax  = ws + OFF_PMAX;
    float* bmax  = ws + OFF_BMAX;
    float* invz  = ws + OFF_INVZ;
    double* pz   = (double*)(ws + OFF_PZ);
    float* Y3    = ws + OFF_Y3;       // [64][384][1024]; later aliased as out0 [64][256][1024]
    float* sat   = ws + OFF_SAT;      // [64][128][1024]
    float* P     = ws + OFF_P;        // [16][1024][1024] chunk logits -> exp
    float* out0  = Y3;                // alias (Y3 dead after PV gemm of last chunk)

    // K0: stack theta/phi/gamma params
    stack_params<<<384, 256, 0, stream>>>(theta_w, theta_b, theta_g, theta_be,
                                          phi_w, phi_b, phi_g, phi_be,
                                          gamma_w, gamma_b, gamma_g, gamma_be, Wst, vecs);

    // K1: conv1x1 stack: Y3[b,o,n] = Wst[o,:] . x[b,:,n] + bias[o]   (M=384,K=256,J=1024)
    gemm_kernel<false><<<dim3(16, 6, 64), 256, 0, stream>>>(
        Wst, 0, 256, x, 256 * 1024, 1024, Y3, 384 * 1024, 1024, 256, vecs, nullptr);

    // K2: BN stats for 384 channels -> scale/shift
    stats_kernel<<<384, 256, 0, stream>>>(Y3, 384 * 1024, vecs + 384, vecs + 768, st1);

    // K3: normalize Y3 in place
    norm_kernel<<<4096, 256, 0, stream>>>((float4*)Y3, st1, 64L * 384 * 256, 384);

    // ---- attention middle, 4 chunks of 16 batch elements ----
    for (int c = 0; c < NCHUNK; ++c) {
        const long b0 = (long)c * BCHUNK;
        const float* Yc = Y3 + b0 * 384 * 1024;

        // K4: logits S[b][m,n] = sum_ch p[ch,m] t[ch,n]
        gemm_kernel<true><<<dim3(16, 16, BCHUNK), 256, 0, stream>>>(
            Yc + 128 * 1024, 384 * 1024, 1024, Yc, 384 * 1024, 1024,
            P, 1024 * 1024, 1024, 128, nullptr, nullptr);

        // K5: per-batch whole-matrix max
        max_kernel<<<dim3(128, BCHUNK), 256, 0, stream>>>(P, pmax + b0 * 128);
        max_reduce_kernel<<<BCHUNK, 128, 0, stream>>>(pmax + b0 * 128, bmax + b0);

        // K6: P = exp(S - max), Z per batch
        expsum_kernel<<<dim3(128, BCHUNK), 256, 0, stream>>>(P, bmax + b0, pz + b0 * 128);
        z_reduce_kernel<<<BCHUNK, 128, 0, stream>>>(pz + b0 * 128, invz + b0);

        // K7: sat[b][ch,n] = invZ * sum_m g[ch,m] P[m,n]   (M=128,K=1024,J=1024)
        gemm_kernel<false><<<dim3(16, 2, BCHUNK), 256, 0, stream>>>(
            Yc + 256 * 1024, 384 * 1024, 1024, P, 1024 * 1024, 1024,
            sat + b0 * 128 * 1024, 128 * 1024, 1024, 1024, nullptr, invz + b0);
    }

    // K8: omega conv: out0[b,o,n] = omega_w[o,:] . sat[b,:,n] + omega_b[o]  (M=256,K=128,J=1024)
    gemm_kernel<false><<<dim3(16, 4, 64), 256, 0, stream>>>(
        omega_w, 0, 128, sat, 128 * 1024, 1024, out0, 256 * 1024, 1024, 128, omega_b, nullptr);

    // K9: BN stats for 256 output channels
    stats_kernel<<<256, 256, 0, stream>>>(out0, 256 * 1024, omega_g, omega_be, st2);

    // K10: out = x + BN(out0)
    final_kernel<<<4096, 256, 0, stream>>>((const float4*)x, (const float4*)out0, st2,
                                           (float4*)out, 64L * 256 * 256);
}

// Round 4
// 792.495 us; speedup vs baseline: 1.9341x; 1.9341x over previous
//
#include <hip/hip_runtime.h>
#include <cstdio>

// B=64, CIN=256, CP=128, N=1024. Stacked conv: 384 = theta|phi|gamma.
// All GEMMs as A[M][k] x Bt[N][k] (k-contiguous both sides), MFMA 16x16x32 bf16.
// Split-bf16 (hi+lo, 3 products) for conv1 + QK^T (softmax is near-argmax: logit
// error must be <~1e-2 absolute); plain bf16 for PV + omega.
// Output writes are Ct[N][M] (lane holds 4 consecutive M-rows of one N-col).

typedef __attribute__((ext_vector_type(4))) float f32x4;
typedef __attribute__((ext_vector_type(8))) short short8;
typedef __attribute__((ext_vector_type(4))) unsigned short u16x4;

static constexpr int BCHUNK = 16;

// ---- workspace layout (floats) ----
static constexpr long OFF_WST  = 0;          // 98304
static constexpr long OFF_VEC  = 98304;      // 1152: b|g|beta stacked
static constexpr long OFF_R1   = 99456;      // 768: st1 raw sums (384 sum | 384 sumsq)
static constexpr long OFF_SC1  = 100224;     // 384
static constexpr long OFF_SH1  = 100608;     // 384
static constexpr long OFF_R2   = 100992;     // 512
static constexpr long OFF_SC2  = 101504;     // 256
static constexpr long OFF_SH2  = 101760;     // 256
static constexpr long OFF_PMAX = 102016;     // 8192
static constexpr long OFF_BMAX = 110208;     // 64
static constexpr long OFF_INVZ = 110272;     // 64
static constexpr long OFF_PZ   = 110336;     // 16384 (as doubles: 8192)
static constexpr long OFF_A    = 131072;     // 16777216: xT hi/lo -> tpT hi/lo -> out0T f32
static constexpr long OFF_B    = OFF_A + 16777216;  // 25165824: YT f32 -> P f32 (chunk)
static constexpr long OFF_C    = OFF_B + 25165824;  // 4194304: g bf16 [64][128][1024]
static constexpr long OFF_D    = OFF_C + 4194304;   // 4194304: satT bf16 [64][1024][128]
static constexpr long WS_FLOATS = OFF_D + 4194304;  // 50462720 (~202 MB)

__device__ __forceinline__ unsigned short f2bf(float f) {
    union { float f; unsigned u; } x; x.f = f;
    unsigned r = x.u + 0x7FFF + ((x.u >> 16) & 1);
    return (unsigned short)(r >> 16);
}
__device__ __forceinline__ float bf2f(unsigned short h) {
    union { unsigned u; float f; } x; x.u = ((unsigned)h) << 16; return x.f;
}

// ---------------- utility kernels ----------------
__global__ void zero2(float* p1, int n1, float* p2, int n2) {
    int i = blockIdx.x * 256 + threadIdx.x;
    if (i < n1) p1[i] = 0.f;
    if (i < n2) p2[i] = 0.f;
}

__global__ void stack_params(const float* tw, const float* tb, const float* tg, const float* tbe,
                             const float* pw, const float* pb, const float* pg, const float* pbe,
                             const float* gw, const float* gb, const float* gg, const float* gbe,
                             float* Wst, float* vecs) {
    int i = blockIdx.x * 256 + threadIdx.x;
    if (i < 98304) {
        int o = i >> 8, c = i & 255;
        float v = (o < 128) ? tw[o * 256 + c] : (o < 256) ? pw[(o - 128) * 256 + c]
                                                          : gw[(o - 256) * 256 + c];
        Wst[i] = v;
    }
    if (i < 384) {
        float b  = (i < 128) ? tb[i]  : (i < 256) ? pb[i - 128]  : gb[i - 256];
        float g  = (i < 128) ? tg[i]  : (i < 256) ? pg[i - 128]  : gg[i - 256];
        float be = (i < 128) ? tbe[i] : (i < 256) ? pbe[i - 128] : gbe[i - 256];
        vecs[i] = b; vecs[384 + i] = g; vecs[768 + i] = be;
    }
}

// x [64][256][1024] f32 -> xT [64][1024][256] bf16 hi/lo
__global__ __launch_bounds__(256) void transpose_x(const float* __restrict__ x,
                                                   unsigned short* __restrict__ xh,
                                                   unsigned short* __restrict__ xl) {
    __shared__ float t[64][68];
    const int b = blockIdx.z, c0 = blockIdx.y * 64, n0 = blockIdx.x * 64;
    const int tid = threadIdx.x;
#pragma unroll
    for (int p = 0; p < 4; ++p) {
        int i = tid + p * 256;
        int c = i >> 4, n4 = (i & 15) << 2;
        f32x4 v = *(const f32x4*)&x[((long)b * 256 + c0 + c) * 1024 + n0 + n4];
        *(f32x4*)&t[c][n4] = v;
    }
    __syncthreads();
#pragma unroll
    for (int p = 0; p < 4; ++p) {
        int i = tid + p * 256;
        int n = i >> 4, c4 = (i & 15) << 2;
        u16x4 h, l;
#pragma unroll
        for (int j = 0; j < 4; ++j) {
            float v = t[c4 + j][n];
            unsigned short hh = f2bf(v);
            h[j] = hh;
            l[j] = f2bf(v - bf2f(hh));
        }
        long o = ((long)b * 1024 + n0 + n) * 256 + c0 + c4;
        *(u16x4*)&xh[o] = h;
        *(u16x4*)&xl[o] = l;
    }
}

// ---------------- unified MFMA GEMM ----------------
enum Src { F32S, PRE, F32B, B16 };

template <Src S>
__device__ __forceinline__ void stage_tile(const void* hp, const void* lp, long base, int ld,
                                           int row0, int kt, unsigned short* sh,
                                           unsigned short* sl, int tid) {
#pragma unroll
    for (int p = 0; p < 4; ++p) {
        int g = tid + p * 256;
        int row = g >> 3, kq = (g & 7) << 2;
        long gi = base + (long)(row0 + row) * ld + kt + kq;
        u16x4 h, l;
        if constexpr (S == F32S || S == F32B) {
            f32x4 v = *(const f32x4*)((const float*)hp + gi);
#pragma unroll
            for (int j = 0; j < 4; ++j) h[j] = f2bf(v[j]);
            if constexpr (S == F32S) {
#pragma unroll
                for (int j = 0; j < 4; ++j) l[j] = f2bf(v[j] - bf2f(h[j]));
            }
        } else {
            h = *(const u16x4*)((const unsigned short*)hp + gi);
            if constexpr (S == PRE) l = *(const u16x4*)((const unsigned short*)lp + gi);
        }
        *(u16x4*)&sh[row * 40 + kq] = h;
        if constexpr (S == F32S || S == PRE) *(u16x4*)&sl[row * 40 + kq] = l;
    }
}

// C-tile 128x128 per block (4 waves, each 64x64 via 4x4 frags of 16x16x32).
// Output: Ct[N-col][M-row] (ldc = M size). Optional bias[M], per-z scale, atomic stats.
template <Src AS, Src BS, bool OUT_BF16, bool HAS_BIAS, bool HAS_SCALE, bool STATS>
__global__ __launch_bounds__(256) void mgemm(
    const void* __restrict__ Ah, const void* __restrict__ Al, long aBatch, long aOff, int lda,
    const void* __restrict__ Bh, const void* __restrict__ Bl, long bBatch, long bOff, int ldb,
    void* __restrict__ Cq, long cBatch, int ldc, int KTOT,
    const float* __restrict__ bias, const float* __restrict__ bscale,
    float* __restrict__ stats, int statStride) {
    constexpr bool SP = (AS == F32S || AS == PRE);
    constexpr int NP = SP ? 4 : 2;
    __shared__ unsigned short lds[NP * 5120];
    unsigned short* Ash = lds;
    unsigned short* Bsh = lds + 5120;
    unsigned short* Asl = SP ? (lds + 2 * 5120) : lds;
    unsigned short* Bsl = SP ? (lds + 3 * 5120) : lds;

    const int tid = threadIdx.x;
    const int wave = tid >> 6, lane = tid & 63;
    const int wm = wave >> 1, wn = wave & 1;
    const int lr = lane & 15, lg = lane >> 4;
    const int z = blockIdx.z;
    const int m0 = blockIdx.y * 128, n0 = blockIdx.x * 128;
    const long aB = aOff + (long)z * aBatch;
    const long bB = bOff + (long)z * bBatch;

    f32x4 acc[4][4];
#pragma unroll
    for (int i = 0; i < 4; ++i)
#pragma unroll
        for (int j = 0; j < 4; ++j) acc[i][j] = (f32x4){0.f, 0.f, 0.f, 0.f};

    for (int kt = 0; kt < KTOT; kt += 32) {
        stage_tile<AS>(Ah, Al, aB, lda, m0, kt, Ash, Asl, tid);
        stage_tile<BS>(Bh, Bl, bB, ldb, n0, kt, Bsh, Bsl, tid);
        __syncthreads();
        short8 ah[4], bh[4], al[4], bl[4];
#pragma unroll
        for (int i = 0; i < 4; ++i) {
            ah[i] = *(const short8*)&Ash[(wm * 64 + i * 16 + lr) * 40 + lg * 8];
            bh[i] = *(const short8*)&Bsh[(wn * 64 + i * 16 + lr) * 40 + lg * 8];
            if constexpr (SP) {
                al[i] = *(const short8*)&Asl[(wm * 64 + i * 16 + lr) * 40 + lg * 8];
                bl[i] = *(const short8*)&Bsl[(wn * 64 + i * 16 + lr) * 40 + lg * 8];
            }
        }
#pragma unroll
        for (int mi = 0; mi < 4; ++mi)
#pragma unroll
            for (int ni = 0; ni < 4; ++ni) {
                acc[mi][ni] = __builtin_amdgcn_mfma_f32_16x16x32_bf16(ah[mi], bh[ni],
                                                                     acc[mi][ni], 0, 0, 0);
                if constexpr (SP) {
                    acc[mi][ni] = __builtin_amdgcn_mfma_f32_16x16x32_bf16(ah[mi], bl[ni],
                                                                         acc[mi][ni], 0, 0, 0);
                    acc[mi][ni] = __builtin_amdgcn_mfma_f32_16x16x32_bf16(al[mi], bh[ni],
                                                                         acc[mi][ni], 0, 0, 0);
                }
            }
        __syncthreads();
    }

    const float sc = HAS_SCALE ? bscale[z] : 1.0f;
#pragma unroll
    for (int mi = 0; mi < 4; ++mi) {
        const int mrow = m0 + wm * 64 + mi * 16 + lg * 4;
        f32x4 bi = (f32x4){0.f, 0.f, 0.f, 0.f};
        if constexpr (HAS_BIAS) bi = *(const f32x4*)&bias[mrow];
        f32x4 s = (f32x4){0.f, 0.f, 0.f, 0.f}, s2 = s;
#pragma unroll
        for (int ni = 0; ni < 4; ++ni) {
            const int col = n0 + wn * 64 + ni * 16 + lr;
            f32x4 v = acc[mi][ni] * sc + bi;
            if constexpr (STATS) { s += v; s2 += v * v; }
            long ci = (long)z * cBatch + (long)col * ldc + mrow;
            if constexpr (OUT_BF16) {
                u16x4 o;
#pragma unroll
                for (int j = 0; j < 4; ++j) o[j] = f2bf(v[j]);
                *(u16x4*)((unsigned short*)Cq + ci) = o;
            } else {
                *(f32x4*)((float*)Cq + ci) = v;
            }
        }
        if constexpr (STATS) {
#pragma unroll
            for (int m = 1; m < 16; m <<= 1) {
#pragma unroll
                for (int r = 0; r < 4; ++r) {
                    s[r] += __shfl_xor(s[r], m);
                    s2[r] += __shfl_xor(s2[r], m);
                }
            }
            if (lr == 0) {
#pragma unroll
                for (int r = 0; r < 4; ++r) {
                    atomicAdd(&stats[mrow + r], s[r]);
                    atomicAdd(&stats[statStride + mrow + r], s2[r]);
                }
            }
        }
    }
}

// raw sums -> per-channel scale/shift
__global__ void finalize_stats(const float* __restrict__ raw, int n, int stride,
                               const float* __restrict__ g, const float* __restrict__ beta,
                               float* __restrict__ osc, float* __restrict__ osh) {
    int ch = blockIdx.x * 256 + threadIdx.x;
    if (ch < n) {
        double mean = (double)raw[ch] / 65536.0;
        double var = (double)raw[stride + ch] / 65536.0 - mean * mean;
        double s = (double)g[ch] / sqrt(var + 1e-5);
        osc[ch] = (float)s;
        osh[ch] = (float)((double)beta[ch] - mean * s);
    }
}

// normalize theta/phi cols (0..255) of YT -> split bf16 planes tpT [row][256]
__global__ __launch_bounds__(256) void norm_tp(const float* __restrict__ YT,
                                               const float* __restrict__ sc,
                                               const float* __restrict__ sh,
                                               unsigned short* __restrict__ th,
                                               unsigned short* __restrict__ tl) {
    const long total = 64L * 1024 * 64;  // f4 groups
    for (long idx = (long)blockIdx.x * 256 + threadIdx.x; idx < total;
         idx += (long)gridDim.x * 256) {
        long row = idx >> 6;
        int cg = (int)(idx & 63) << 2;
        f32x4 v = *(const f32x4*)&YT[row * 384 + cg];
        f32x4 scv = *(const f32x4*)&sc[cg];
        f32x4 shv = *(const f32x4*)&sh[cg];
        v = v * scv + shv;
        u16x4 h, l;
#pragma unroll
        for (int j = 0; j < 4; ++j) {
            unsigned short hh = f2bf(v[j]);
            h[j] = hh;
            l[j] = f2bf(v[j] - bf2f(hh));
        }
        *(u16x4*)&th[row * 256 + cg] = h;
        *(u16x4*)&tl[row * 256 + cg] = l;
    }
}

// normalize gamma cols (256..383) of YT, transpose -> g bf16 [64][128][1024]
__global__ __launch_bounds__(256) void norm_g(const float* __restrict__ YT,
                                              const float* __restrict__ sc,
                                              const float* __restrict__ sh,
                                              unsigned short* __restrict__ g) {
    __shared__ float t[64][68];
    const int b = blockIdx.z, c0 = blockIdx.y * 64, n0 = blockIdx.x * 64;
    const int tid = threadIdx.x;
#pragma unroll
    for (int p = 0; p < 4; ++p) {
        int i = tid + p * 256;
        int n = i >> 4, c4 = (i & 15) << 2;
        f32x4 v = *(const f32x4*)&YT[((long)b * 1024 + n0 + n) * 384 + 256 + c0 + c4];
        f32x4 scv = *(const f32x4*)&sc[256 + c0 + c4];
        f32x4 shv = *(const f32x4*)&sh[256 + c0 + c4];
        v = v * scv + shv;
        *(f32x4*)&t[n][c4] = v;
    }
    __syncthreads();
#pragma unroll
    for (int p = 0; p < 4; ++p) {
        int i = tid + p * 256;
        int c = i >> 4, n4 = (i & 15) << 2;
        u16x4 o;
#pragma unroll
        for (int j = 0; j < 4; ++j) o[j] = f2bf(t[n4 + j][c]);
        *(u16x4*)&g[((long)b * 128 + c0 + c) * 1024 + n0 + n4] = o;
    }
}

// ---------------- softmax pieces (per batch element, chunk-local P) ----------------
__global__ __launch_bounds__(256) void max_kernel(const float* __restrict__ S,
                                                  float* __restrict__ pmax) {
    const int b = blockIdx.y, blk = blockIdx.x;
    const float* p = S + (long)b * 1048576 + (long)blk * 8192;
    float m = -3.4e38f;
    for (int i = threadIdx.x; i < 8192; i += 256) m = fmaxf(m, p[i]);
    __shared__ float lm[256];
    lm[threadIdx.x] = m;
    __syncthreads();
    for (int o = 128; o > 0; o >>= 1) {
        if (threadIdx.x < o) lm[threadIdx.x] = fmaxf(lm[threadIdx.x], lm[threadIdx.x + o]);
        __syncthreads();
    }
    if (threadIdx.x == 0) pmax[b * 128 + blk] = lm[0];
}

__global__ __launch_bounds__(128) void max_reduce_kernel(const float* __restrict__ pmax,
                                                         float* __restrict__ bmax) {
    const int b = blockIdx.x;
    __shared__ float lm[128];
    lm[threadIdx.x] = pmax[b * 128 + threadIdx.x];
    __syncthreads();
    for (int o = 64; o > 0; o >>= 1) {
        if (threadIdx.x < o) lm[threadIdx.x] = fmaxf(lm[threadIdx.x], lm[threadIdx.x + o]);
        __syncthreads();
    }
    if (threadIdx.x == 0) bmax[b] = lm[0];
}

__global__ __launch_bounds__(256) void expsum_kernel(float* __restrict__ S,
                                                     const float* __restrict__ bmax,
                                                     double* __restrict__ pz) {
    const int b = blockIdx.y, blk = blockIdx.x;
    const float mb = bmax[b];
    float* p = S + (long)b * 1048576 + (long)blk * 8192;
    double s = 0.0;
    for (int i = threadIdx.x; i < 8192; i += 256) {
        float e = expf(p[i] - mb);
        p[i] = e;
        s += e;
    }
    __shared__ double ls[256];
    ls[threadIdx.x] = s;
    __syncthreads();
    for (int o = 128; o > 0; o >>= 1) {
        if (threadIdx.x < o) ls[threadIdx.x] += ls[threadIdx.x + o];
        __syncthreads();
    }
    if (threadIdx.x == 0) pz[b * 128 + blk] = ls[0];
}

__global__ __launch_bounds__(128) void z_reduce_kernel(const double* __restrict__ pz,
                                                       float* __restrict__ invz) {
    const int b = blockIdx.x;
    __shared__ double l[128];
    l[threadIdx.x] = pz[b * 128 + threadIdx.x];
    __syncthreads();
    for (int o = 64; o > 0; o >>= 1) {
        if (threadIdx.x < o) l[threadIdx.x] += l[threadIdx.x + o];
        __syncthreads();
    }
    if (threadIdx.x == 0) invz[b] = (float)(1.0 / l[0]);
}

// out[b][oc][n] = x + sc2[oc]*out0T[b][n][oc] + sh2[oc]  (LDS tile transpose)
__global__ __launch_bounds__(256) void final_kernel(const float* __restrict__ x,
                                                    const float* __restrict__ out0T,
                                                    const float* __restrict__ sc,
                                                    const float* __restrict__ sh,
                                                    float* __restrict__ out) {
    __shared__ float t[64][68];
    const int b = blockIdx.z, oc0 = blockIdx.y * 64, n0 = blockIdx.x * 64;
    const int tid = threadIdx.x;
#pragma unroll
    for (int p = 0; p < 4; ++p) {
        int i = tid + p * 256;
        int n = i >> 4, c4 = (i & 15) << 2;
        f32x4 v = *(const f32x4*)&out0T[((long)b * 1024 + n0 + n) * 256 + oc0 + c4];
        *(f32x4*)&t[n][c4] = v;
    }
    __syncthreads();
#pragma unroll
    for (int p = 0; p < 4; ++p) {
        int i = tid + p * 256;
        int oc = i >> 4, n4 = (i & 15) << 2;
        const float scv = sc[oc0 + oc], shv = sh[oc0 + oc];
        long o = ((long)b * 256 + oc0 + oc) * 1024 + n0 + n4;
        f32x4 xv = *(const f32x4*)&x[o];
        f32x4 v;
#pragma unroll
        for (int j = 0; j < 4; ++j) v[j] = xv[j] + t[n4 + j][oc] * scv + shv;
        *(f32x4*)&out[o] = v;
    }
}

extern "C" void kernel_launch(void* const* d_in, const int* in_sizes, int n_in,
                              void* d_out, int out_size, void* d_ws, size_t ws_size,
                              hipStream_t stream) {
    const float* x        = (const float*)d_in[0];
    const float* theta_w  = (const float*)d_in[1];
    const float* theta_b  = (const float*)d_in[2];
    const float* theta_g  = (const float*)d_in[3];
    const float* theta_be = (const float*)d_in[4];
    const float* phi_w    = (const float*)d_in[5];
    const float* phi_b    = (const float*)d_in[6];
    const float* phi_g    = (const float*)d_in[7];
    const float* phi_be   = (const float*)d_in[8];
    const float* gamma_w  = (const float*)d_in[9];
    const float* gamma_b  = (const float*)d_in[10];
    const float* gamma_g  = (const float*)d_in[11];
    const float* gamma_be = (const float*)d_in[12];
    const float* omega_w  = (const float*)d_in[13];
    const float* omega_b  = (const float*)d_in[14];
    const float* omega_g  = (const float*)d_in[15];
    const float* omega_be = (const float*)d_in[16];
    float* out = (float*)d_out;

    const size_t need = (size_t)WS_FLOATS * 4;
    if (ws_size < need) {
        fprintf(stderr, "kernel_launch: ws_size %zu < needed %zu\n", ws_size, need);
        return;
    }
    float* ws = (float*)d_ws;
    float* Wst  = ws + OFF_WST;
    float* vecs = ws + OFF_VEC;
    float* r1   = ws + OFF_R1;
    float* sc1  = ws + OFF_SC1;
    float* sh1  = ws + OFF_SH1;
    float* r2   = ws + OFF_R2;
    float* sc2  = ws + OFF_SC2;
    float* sh2  = ws + OFF_SH2;
    float* pmax = ws + OFF_PMAX;
    float* bmax = ws + OFF_BMAX;
    float* invz = ws + OFF_INVZ;
    double* pz  = (double*)(ws + OFF_PZ);
    unsigned short* xh  = (unsigned short*)(ws + OFF_A);            // also tpT hi
    unsigned short* xl  = (unsigned short*)(ws + OFF_A + 8388608);  // also tpT lo
    float* out0T        = ws + OFF_A;                               // overlays xT/tpT
    float* YT           = ws + OFF_B;                               // [64*1024][384]
    float* P            = ws + OFF_B;                               // [16][1024][1024] overlays YT
    unsigned short* g   = (unsigned short*)(ws + OFF_C);            // [64][128][1024]
    unsigned short* satT= (unsigned short*)(ws + OFF_D);            // [64][1024][128]

    zero2<<<3, 256, 0, stream>>>(r1, 768, r2, 512);
    stack_params<<<384, 256, 0, stream>>>(theta_w, theta_b, theta_g, theta_be,
                                          phi_w, phi_b, phi_g, phi_be,
                                          gamma_w, gamma_b, gamma_g, gamma_be, Wst, vecs);
    transpose_x<<<dim3(16, 4, 64), 256, 0, stream>>>(x, xh, xl);

    // K1: YT[b*1024+n][oc] = Wst[oc][:] . x[b][:][n] + bias  (split bf16, stats fused)
    mgemm<F32S, PRE, false, true, false, true><<<dim3(8, 3, 64), 256, 0, stream>>>(
        Wst, nullptr, 0, 0, 256, xh, xl, 262144, 0, 256,
        YT, 393216, 384, 256, vecs, nullptr, r1, 384);
    finalize_stats<<<2, 256, 0, stream>>>(r1, 384, 384, vecs + 384, vecs + 768, sc1, sh1);

    norm_tp<<<4096, 256, 0, stream>>>(YT, sc1, sh1, xh, xl);  // tpT planes (overwrite xT)
    norm_g<<<dim3(16, 2, 64), 256, 0, stream>>>(YT, sc1, sh1, g);

    for (int c = 0; c < 4; ++c) {
        const long b0 = (long)c * BCHUNK;
        // K4: P[n][m] = attn-logits = sum_c pT[m][c] tT[n][c]  (split bf16)
        mgemm<PRE, PRE, false, false, false, false><<<dim3(8, 8, BCHUNK), 256, 0, stream>>>(
            xh, xl, 262144, b0 * 262144 + 128, 256,
            xh, xl, 262144, b0 * 262144 + 0, 256,
            P, 1048576, 1024, 128, nullptr, nullptr, nullptr, 0);

        max_kernel<<<dim3(128, BCHUNK), 256, 0, stream>>>(P, pmax);
        max_reduce_kernel<<<BCHUNK, 128, 0, stream>>>(pmax, bmax);
        expsum_kernel<<<dim3(128, BCHUNK), 256, 0, stream>>>(P, bmax, pz);
        z_reduce_kernel<<<BCHUNK, 128, 0, stream>>>(pz, invz + b0);

        // K7: satT[n][c] = invz * sum_m g[c][m] P[n][m]  (bf16)
        mgemm<B16, F32B, true, false, true, false><<<dim3(8, 1, BCHUNK), 256, 0, stream>>>(
            g, nullptr, 131072, b0 * 131072, 1024,
            P, nullptr, 1048576, 0, 1024,
            satT + b0 * 131072, 131072, 128, 1024, nullptr, invz + b0, nullptr, 0);
    }

    // K8: out0T[b*1024+n][oc] = omega_w[oc][:] . sat[:][n] + omega_b  (bf16, stats fused)
    mgemm<F32B, B16, false, true, false, true><<<dim3(8, 2, 64), 256, 0, stream>>>(
        omega_w, nullptr, 0, 0, 128, satT, nullptr, 131072, 0, 128,
        out0T, 262144, 256, 128, omega_b, nullptr, r2, 256);
    finalize_stats<<<1, 256, 0, stream>>>(r2, 256, 256, omega_g, omega_be, sc2, sh2);

    final_kernel<<<dim3(16, 4, 64), 256, 0, stream>>>(x, out0T, sc2, sh2, out);
}

// Round 5
// 725.500 us; speedup vs baseline: 2.1127x; 1.0923x over previous
//
#include <hip/hip_runtime.h>
#include <cstdio>

// B=64, CIN=256, CP=128, N=1024. Stacked conv: 384 = theta|phi|gamma.
// GEMMs as A[M][k] x Bt[N][k], MFMA 16x16x32 bf16, split-bf16 (3 products) for
// conv1 + QK^T, plain bf16 for PV + omega. Softmax fused: QK^T epilogue does
// atomicMax(batch max); PV staging computes exp(S-max) (each P elem staged once)
// and accumulates Z; 1/Z folded into omega's per-batch epilogue scale.

typedef __attribute__((ext_vector_type(4))) float f32x4;
typedef __attribute__((ext_vector_type(8))) short short8;
typedef __attribute__((ext_vector_type(4))) unsigned short u16x4;

static constexpr int BCHUNK = 16;

// ---- workspace layout (floats) ----
static constexpr long OFF_WST  = 0;          // 98304
static constexpr long OFF_VEC  = 98304;      // 1152: b|g|beta stacked
static constexpr long OFF_R1   = 99456;      // 768  (zeroed region start)
static constexpr long OFF_R2   = 100224;     // 512
static constexpr long OFF_ZS   = 100736;     // 64
static constexpr long OFF_AM   = 100800;     // 64 (uint)   (zeroed region: 1408)
static constexpr long OFF_SC1  = 100864;     // 384
static constexpr long OFF_SH1  = 101248;     // 384
static constexpr long OFF_SC2  = 101632;     // 256
static constexpr long OFF_SH2  = 101888;     // 256
static constexpr long OFF_INVZ = 102144;     // 64
static constexpr long OFF_A    = 131072;               // 16777216: xT hi/lo -> tpT hi/lo -> out0T f32
static constexpr long OFF_B    = OFF_A + 16777216;     // 25165824: YT f32 -> P f32 (chunk)
static constexpr long OFF_C    = OFF_B + 25165824;     // 4194304: g bf16 [64][128][1024]
static constexpr long OFF_D    = OFF_C + 4194304;      // 4194304: satT bf16 [64][1024][128]
static constexpr long WS_FLOATS = OFF_D + 4194304;     // ~202 MB

__device__ __forceinline__ unsigned short f2bf(float f) {
    union { float f; unsigned u; } x; x.f = f;
    unsigned r = x.u + 0x7FFF + ((x.u >> 16) & 1);
    return (unsigned short)(r >> 16);
}
__device__ __forceinline__ float bf2f(unsigned short h) {
    union { unsigned u; float f; } x; x.u = ((unsigned)h) << 16; return x.f;
}
// monotone float<->uint order encoding for atomicMax on signed floats
__device__ __forceinline__ unsigned fenc(float f) {
    unsigned u = __float_as_uint(f);
    return (u & 0x80000000u) ? ~u : (u | 0x80000000u);
}
__device__ __forceinline__ float fdec(unsigned e) {
    return __uint_as_float((e & 0x80000000u) ? (e & 0x7fffffffu) : ~e);
}

// ---------------- utility kernels ----------------
__global__ void zero_n(float* p, int n) {
    int i = blockIdx.x * 256 + threadIdx.x;
    if (i < n) p[i] = 0.f;
}

__global__ void invz_kernel(const float* zs, float* invz) {
    int i = threadIdx.x;
    if (i < 64) invz[i] = 1.0f / zs[i];
}

__global__ void stack_params(const float* tw, const float* tb, const float* tg, const float* tbe,
                             const float* pw, const float* pb, const float* pg, const float* pbe,
                             const float* gw, const float* gb, const float* gg, const float* gbe,
                             float* Wst, float* vecs) {
    int i = blockIdx.x * 256 + threadIdx.x;
    if (i < 98304) {
        int o = i >> 8, c = i & 255;
        float v = (o < 128) ? tw[o * 256 + c] : (o < 256) ? pw[(o - 128) * 256 + c]
                                                          : gw[(o - 256) * 256 + c];
        Wst[i] = v;
    }
    if (i < 384) {
        float b  = (i < 128) ? tb[i]  : (i < 256) ? pb[i - 128]  : gb[i - 256];
        float g  = (i < 128) ? tg[i]  : (i < 256) ? pg[i - 128]  : gg[i - 256];
        float be = (i < 128) ? tbe[i] : (i < 256) ? pbe[i - 128] : gbe[i - 256];
        vecs[i] = b; vecs[384 + i] = g; vecs[768 + i] = be;
    }
}

// x [64][256][1024] f32 -> xT [64][1024][256] bf16 hi/lo
__global__ __launch_bounds__(256) void transpose_x(const float* __restrict__ x,
                                                   unsigned short* __restrict__ xh,
                                                   unsigned short* __restrict__ xl) {
    __shared__ float t[64][68];
    const int b = blockIdx.z, c0 = blockIdx.y * 64, n0 = blockIdx.x * 64;
    const int tid = threadIdx.x;
#pragma unroll
    for (int p = 0; p < 4; ++p) {
        int i = tid + p * 256;
        int c = i >> 4, n4 = (i & 15) << 2;
        f32x4 v = *(const f32x4*)&x[((long)b * 256 + c0 + c) * 1024 + n0 + n4];
        *(f32x4*)&t[c][n4] = v;
    }
    __syncthreads();
#pragma unroll
    for (int p = 0; p < 4; ++p) {
        int i = tid + p * 256;
        int n = i >> 4, c4 = (i & 15) << 2;
        u16x4 h, l;
#pragma unroll
        for (int j = 0; j < 4; ++j) {
            float v = t[c4 + j][n];
            unsigned short hh = f2bf(v);
            h[j] = hh;
            l[j] = f2bf(v - bf2f(hh));
        }
        long o = ((long)b * 1024 + n0 + n) * 256 + c0 + c4;
        *(u16x4*)&xh[o] = h;
        *(u16x4*)&xl[o] = l;
    }
}

// ---------------- unified MFMA GEMM ----------------
// Src of a staged operand: F32S f32->split hi/lo; PRE pre-split bf16 hi/lo planes;
// F32B f32->bf16 (round); B16 plain bf16; EXPF f32 logits -> exp(v-max) bf16 + Z-sum.
enum Src { F32S, PRE, F32B, B16, EXPF };

template <Src S, int ROWS>
struct Stage {
    static constexpr int P = ROWS / 32;
    f32x4 raw[(S == F32S || S == F32B || S == EXPF) ? P : 1];
    u16x4 h[(S == PRE || S == B16) ? P : 1];
    u16x4 l[(S == PRE) ? P : 1];

    __device__ __forceinline__ void load(const void* hp, const void* lp, long base,
                                         int ld, int row0, int kt, int tid) {
#pragma unroll
        for (int p = 0; p < P; ++p) {
            int g = tid + p * 256;
            int row = g >> 3, kq = (g & 7) << 2;
            long gi = base + (long)(row0 + row) * ld + kt + kq;
            if constexpr (S == F32S || S == F32B || S == EXPF) {
                raw[p] = *(const f32x4*)((const float*)hp + gi);
            } else {
                h[p] = *(const u16x4*)((const unsigned short*)hp + gi);
                if constexpr (S == PRE) l[p] = *(const u16x4*)((const unsigned short*)lp + gi);
            }
        }
    }
    __device__ __forceinline__ void write(unsigned short* sh, unsigned short* sl, int tid,
                                          float mb, float& zacc) {
#pragma unroll
        for (int p = 0; p < P; ++p) {
            int g = tid + p * 256;
            int row = g >> 3, kq = (g & 7) << 2;
            u16x4 hh, ll;
            if constexpr (S == F32S) {
#pragma unroll
                for (int j = 0; j < 4; ++j) {
                    hh[j] = f2bf(raw[p][j]);
                    ll[j] = f2bf(raw[p][j] - bf2f(hh[j]));
                }
            } else if constexpr (S == EXPF) {
#pragma unroll
                for (int j = 0; j < 4; ++j) {
                    float e = exp2f((raw[p][j] - mb) * 1.4426950408889634f);
                    zacc += e;
                    hh[j] = f2bf(e);
                }
            } else if constexpr (S == F32B) {
#pragma unroll
                for (int j = 0; j < 4; ++j) hh[j] = f2bf(raw[p][j]);
            } else {
                hh = h[p];
                if constexpr (S == PRE) ll = l[p];
            }
            *(u16x4*)&sh[row * 40 + kq] = hh;
            if constexpr (S == F32S || S == PRE) *(u16x4*)&sl[row * 40 + kq] = ll;
        }
    }
};

// Block tile 128 x (NF*32), 4 waves as 2x2; wave tile 64 x (NF*16), frags 4xNF.
// Output Ct[N-col][M-row]. Reg-staged pipeline: load(k+1) -> mfma(k) -> sync ->
// write(k+1) -> sync.
template <Src AS, Src BS, int NF, bool OUT_BF16, bool HAS_BIAS, bool HAS_SCALE,
          bool STATS, bool AMAX>
__global__ __launch_bounds__(256) void mgemm(
    const void* __restrict__ Ah, const void* __restrict__ Al, long aBatch, long aOff, int lda,
    const void* __restrict__ Bh, const void* __restrict__ Bl, long bBatch, long bOff, int ldb,
    void* __restrict__ Cq, long cBatch, int ldc, int KTOT,
    const float* __restrict__ bias, const float* __restrict__ bscale,
    float* __restrict__ stats, int statStride,
    unsigned* __restrict__ amax, float* __restrict__ zsum) {
    constexpr bool SP = (AS == F32S || AS == PRE);
    constexpr int BROWS = NF * 32;
    constexpr int ASZ = 128 * 40, BSZ = BROWS * 40;
    __shared__ unsigned short lds[(SP ? 2 : 1) * (ASZ + BSZ)];
    unsigned short* Ash = lds;
    unsigned short* Bsh = lds + ASZ;
    unsigned short* Asl = SP ? (lds + ASZ + BSZ) : lds;
    unsigned short* Bsl = SP ? (lds + 2 * ASZ + BSZ) : lds;

    const int tid = threadIdx.x;
    const int wave = tid >> 6, lane = tid & 63;
    const int wm = wave >> 1, wn = wave & 1;
    const int lr = lane & 15, lg = lane >> 4;
    const int z = blockIdx.z;
    const int m0 = blockIdx.y * 128, n0 = blockIdx.x * BROWS;
    const long aB = aOff + (long)z * aBatch;
    const long bB = bOff + (long)z * bBatch;

    float mb = 0.f, zacc = 0.f;
    if constexpr (BS == EXPF) mb = fdec(amax[z]);

    f32x4 acc[4][NF];
#pragma unroll
    for (int i = 0; i < 4; ++i)
#pragma unroll
        for (int j = 0; j < NF; ++j) acc[i][j] = (f32x4){0.f, 0.f, 0.f, 0.f};

    Stage<AS, 128> sA;
    Stage<BS, BROWS> sB;
    sA.load(Ah, Al, aB, lda, m0, 0, tid);
    sB.load(Bh, Bl, bB, ldb, n0, 0, tid);
    sA.write(Ash, Asl, tid, mb, zacc);
    sB.write(Bsh, Bsl, tid, mb, zacc);
    __syncthreads();

    for (int kt = 32; kt < KTOT + 32; kt += 32) {
        const bool more = kt < KTOT;
        if (more) {
            sA.load(Ah, Al, aB, lda, m0, kt, tid);
            sB.load(Bh, Bl, bB, ldb, n0, kt, tid);
        }
        short8 ah[4], al[4];
#pragma unroll
        for (int i = 0; i < 4; ++i) {
            ah[i] = *(const short8*)&Ash[(wm * 64 + i * 16 + lr) * 40 + lg * 8];
            if constexpr (SP) al[i] = *(const short8*)&Asl[(wm * 64 + i * 16 + lr) * 40 + lg * 8];
        }
#pragma unroll
        for (int ni = 0; ni < NF; ++ni) {
            const int brow = (wn * NF * 16 + ni * 16 + lr) * 40 + lg * 8;
            short8 bh = *(const short8*)&Bsh[brow];
#pragma unroll
            for (int mi = 0; mi < 4; ++mi)
                acc[mi][ni] = __builtin_amdgcn_mfma_f32_16x16x32_bf16(ah[mi], bh,
                                                                     acc[mi][ni], 0, 0, 0);
            if constexpr (SP) {
                short8 bl = *(const short8*)&Bsl[brow];
#pragma unroll
                for (int mi = 0; mi < 4; ++mi) {
                    acc[mi][ni] = __builtin_amdgcn_mfma_f32_16x16x32_bf16(ah[mi], bl,
                                                                         acc[mi][ni], 0, 0, 0);
                    acc[mi][ni] = __builtin_amdgcn_mfma_f32_16x16x32_bf16(al[mi], bh,
                                                                         acc[mi][ni], 0, 0, 0);
                }
            }
        }
        __syncthreads();
        if (more) {
            sA.write(Ash, Asl, tid, mb, zacc);
            sB.write(Bsh, Bsl, tid, mb, zacc);
            __syncthreads();
        }
    }

    // Z accumulation (EXPF): block-reduce zacc, one atomic per block
    if constexpr (BS == EXPF) {
        float* red = (float*)lds;
        red[tid] = zacc;
        __syncthreads();
        for (int o = 128; o > 0; o >>= 1) {
            if (tid < o) red[tid] += red[tid + o];
            __syncthreads();
        }
        if (tid == 0) atomicAdd(&zsum[z], red[0]);
    }

    const float sc = HAS_SCALE ? bscale[z] : 1.0f;
    float lmax = -3.4e38f;
#pragma unroll
    for (int mi = 0; mi < 4; ++mi) {
        const int mrow = m0 + wm * 64 + mi * 16 + lg * 4;
        f32x4 bi = (f32x4){0.f, 0.f, 0.f, 0.f};
        if constexpr (HAS_BIAS) bi = *(const f32x4*)&bias[mrow];
        f32x4 s = (f32x4){0.f, 0.f, 0.f, 0.f}, s2 = s;
#pragma unroll
        for (int ni = 0; ni < NF; ++ni) {
            const int col = n0 + wn * NF * 16 + ni * 16 + lr;
            f32x4 v = acc[mi][ni] * sc + bi;
            if constexpr (STATS) { s += v; s2 += v * v; }
            if constexpr (AMAX) {
#pragma unroll
                for (int j = 0; j < 4; ++j) lmax = fmaxf(lmax, v[j]);
            }
            long ci = (long)z * cBatch + (long)col * ldc + mrow;
            if constexpr (OUT_BF16) {
                u16x4 o;
#pragma unroll
                for (int j = 0; j < 4; ++j) o[j] = f2bf(v[j]);
                *(u16x4*)((unsigned short*)Cq + ci) = o;
            } else {
                *(f32x4*)((float*)Cq + ci) = v;
            }
        }
        if constexpr (STATS) {
#pragma unroll
            for (int m = 1; m < 16; m <<= 1) {
#pragma unroll
                for (int r = 0; r < 4; ++r) {
                    s[r] += __shfl_xor(s[r], m);
                    s2[r] += __shfl_xor(s2[r], m);
                }
            }
            if (lr == 0) {
#pragma unroll
                for (int r = 0; r < 4; ++r) {
                    atomicAdd(&stats[mrow + r], s[r]);
                    atomicAdd(&stats[statStride + mrow + r], s2[r]);
                }
            }
        }
    }
    if constexpr (AMAX) {
#pragma unroll
        for (int o = 1; o < 64; o <<= 1) lmax = fmaxf(lmax, __shfl_xor(lmax, o));
        if (lane == 0) atomicMax(&amax[z], fenc(lmax));
    }
}

// raw sums -> per-channel scale/shift
__global__ void finalize_stats(const float* __restrict__ raw, int n, int stride,
                               const float* __restrict__ g, const float* __restrict__ beta,
                               float* __restrict__ osc, float* __restrict__ osh) {
    int ch = blockIdx.x * 256 + threadIdx.x;
    if (ch < n) {
        double mean = (double)raw[ch] / 65536.0;
        double var = (double)raw[stride + ch] / 65536.0 - mean * mean;
        double s = (double)g[ch] / sqrt(var + 1e-5);
        osc[ch] = (float)s;
        osh[ch] = (float)((double)beta[ch] - mean * s);
    }
}

// normalize theta/phi cols (0..255) of YT -> split bf16 planes tpT [row][256]
__global__ __launch_bounds__(256) void norm_tp(const float* __restrict__ YT,
                                               const float* __restrict__ sc,
                                               const float* __restrict__ sh,
                                               unsigned short* __restrict__ th,
                                               unsigned short* __restrict__ tl) {
    const long total = 64L * 1024 * 64;  // f4 groups
    for (long idx = (long)blockIdx.x * 256 + threadIdx.x; idx < total;
         idx += (long)gridDim.x * 256) {
        long row = idx >> 6;
        int cg = (int)(idx & 63) << 2;
        f32x4 v = *(const f32x4*)&YT[row * 384 + cg];
        f32x4 scv = *(const f32x4*)&sc[cg];
        f32x4 shv = *(const f32x4*)&sh[cg];
        v = v * scv + shv;
        u16x4 h, l;
#pragma unroll
        for (int j = 0; j < 4; ++j) {
            unsigned short hh = f2bf(v[j]);
            h[j] = hh;
            l[j] = f2bf(v[j] - bf2f(hh));
        }
        *(u16x4*)&th[row * 256 + cg] = h;
        *(u16x4*)&tl[row * 256 + cg] = l;
    }
}

// normalize gamma cols (256..383) of YT, transpose -> g bf16 [64][128][1024]
__global__ __launch_bounds__(256) void norm_g(const float* __restrict__ YT,
                                              const float* __restrict__ sc,
                                              const float* __restrict__ sh,
                                              unsigned short* __restrict__ g) {
    __shared__ float t[64][68];
    const int b = blockIdx.z, c0 = blockIdx.y * 64, n0 = blockIdx.x * 64;
    const int tid = threadIdx.x;
#pragma unroll
    for (int p = 0; p < 4; ++p) {
        int i = tid + p * 256;
        int n = i >> 4, c4 = (i & 15) << 2;
        f32x4 v = *(const f32x4*)&YT[((long)b * 1024 + n0 + n) * 384 + 256 + c0 + c4];
        f32x4 scv = *(const f32x4*)&sc[256 + c0 + c4];
        f32x4 shv = *(const f32x4*)&sh[256 + c0 + c4];
        v = v * scv + shv;
        *(f32x4*)&t[n][c4] = v;
    }
    __syncthreads();
#pragma unroll
    for (int p = 0; p < 4; ++p) {
        int i = tid + p * 256;
        int c = i >> 4, n4 = (i & 15) << 2;
        u16x4 o;
#pragma unroll
        for (int j = 0; j < 4; ++j) o[j] = f2bf(t[n4 + j][c]);
        *(u16x4*)&g[((long)b * 128 + c0 + c) * 1024 + n0 + n4] = o;
    }
}

// out[b][oc][n] = x + sc2[oc]*out0T[b][n][oc] + sh2[oc]  (LDS tile transpose)
__global__ __launch_bounds__(256) void final_kernel(const float* __restrict__ x,
                                                    const float* __restrict__ out0T,
                                                    const float* __restrict__ sc,
                                                    const float* __restrict__ sh,
                                                    float* __restrict__ out) {
    __shared__ float t[64][68];
    const int b = blockIdx.z, oc0 = blockIdx.y * 64, n0 = blockIdx.x * 64;
    const int tid = threadIdx.x;
#pragma unroll
    for (int p = 0; p < 4; ++p) {
        int i = tid + p * 256;
        int n = i >> 4, c4 = (i & 15) << 2;
        f32x4 v = *(const f32x4*)&out0T[((long)b * 1024 + n0 + n) * 256 + oc0 + c4];
        *(f32x4*)&t[n][c4] = v;
    }
    __syncthreads();
#pragma unroll
    for (int p = 0; p < 4; ++p) {
        int i = tid + p * 256;
        int oc = i >> 4, n4 = (i & 15) << 2;
        const float scv = sc[oc0 + oc], shv = sh[oc0 + oc];
        long o = ((long)b * 256 + oc0 + oc) * 1024 + n0 + n4;
        f32x4 xv = *(const f32x4*)&x[o];
        f32x4 v;
#pragma unroll
        for (int j = 0; j < 4; ++j) v[j] = xv[j] + t[n4 + j][oc] * scv + shv;
        *(f32x4*)&out[o] = v;
    }
}

extern "C" void kernel_launch(void* const* d_in, const int* in_sizes, int n_in,
                              void* d_out, int out_size, void* d_ws, size_t ws_size,
                              hipStream_t stream) {
    const float* x        = (const float*)d_in[0];
    const float* theta_w  = (const float*)d_in[1];
    const float* theta_b  = (const float*)d_in[2];
    const float* theta_g  = (const float*)d_in[3];
    const float* theta_be = (const float*)d_in[4];
    const float* phi_w    = (const float*)d_in[5];
    const float* phi_b    = (const float*)d_in[6];
    const float* phi_g    = (const float*)d_in[7];
    const float* phi_be   = (const float*)d_in[8];
    const float* gamma_w  = (const float*)d_in[9];
    const float* gamma_b  = (const float*)d_in[10];
    const float* gamma_g  = (const float*)d_in[11];
    const float* gamma_be = (const float*)d_in[12];
    const float* omega_w  = (const float*)d_in[13];
    const float* omega_b  = (const float*)d_in[14];
    const float* omega_g  = (const float*)d_in[15];
    const float* omega_be = (const float*)d_in[16];
    float* out = (float*)d_out;

    const size_t need = (size_t)WS_FLOATS * 4;
    if (ws_size < need) {
        fprintf(stderr, "kernel_launch: ws_size %zu < needed %zu\n", ws_size, need);
        return;
    }
    float* ws = (float*)d_ws;
    float* Wst  = ws + OFF_WST;
    float* vecs = ws + OFF_VEC;
    float* r1   = ws + OFF_R1;
    float* r2   = ws + OFF_R2;
    float* zs   = ws + OFF_ZS;
    unsigned* am = (unsigned*)(ws + OFF_AM);
    float* sc1  = ws + OFF_SC1;
    float* sh1  = ws + OFF_SH1;
    float* sc2  = ws + OFF_SC2;
    float* sh2  = ws + OFF_SH2;
    float* invz = ws + OFF_INVZ;
    unsigned short* xh  = (unsigned short*)(ws + OFF_A);            // also tpT hi
    unsigned short* xl  = (unsigned short*)(ws + OFF_A + 8388608);  // also tpT lo
    float* out0T        = ws + OFF_A;                               // overlays xT/tpT
    float* YT           = ws + OFF_B;                               // [64*1024][384]
    float* P            = ws + OFF_B;                               // [16][1024][1024] overlays YT
    unsigned short* g   = (unsigned short*)(ws + OFF_C);            // [64][128][1024]
    unsigned short* satT= (unsigned short*)(ws + OFF_D);            // [64][1024][128]

    // zero r1|r2|zsum|amax (contiguous 1408 floats)
    zero_n<<<6, 256, 0, stream>>>(r1, 1408);
    stack_params<<<384, 256, 0, stream>>>(theta_w, theta_b, theta_g, theta_be,
                                          phi_w, phi_b, phi_g, phi_be,
                                          gamma_w, gamma_b, gamma_g, gamma_be, Wst, vecs);
    transpose_x<<<dim3(16, 4, 64), 256, 0, stream>>>(x, xh, xl);

    // K1: YT[b*1024+n][oc] = Wst[oc][:] . x[b][:][n] + bias  (split, stats fused)
    mgemm<F32S, PRE, 4, false, true, false, true, false><<<dim3(8, 3, 64), 256, 0, stream>>>(
        Wst, nullptr, 0, 0, 256, xh, xl, 262144, 0, 256,
        YT, 393216, 384, 256, vecs, nullptr, r1, 384, nullptr, nullptr);
    finalize_stats<<<2, 256, 0, stream>>>(r1, 384, 384, vecs + 384, vecs + 768, sc1, sh1);

    norm_tp<<<4096, 256, 0, stream>>>(YT, sc1, sh1, xh, xl);  // tpT planes (overwrite xT)
    norm_g<<<dim3(16, 2, 64), 256, 0, stream>>>(YT, sc1, sh1, g);

    for (int c = 0; c < 4; ++c) {
        const long b0 = (long)c * BCHUNK;
        // K4: P[n][m] = logits, epilogue atomicMax -> am[b]
        mgemm<PRE, PRE, 4, false, false, false, false, true><<<dim3(8, 8, BCHUNK), 256, 0, stream>>>(
            xh, xl, 262144, b0 * 262144 + 128, 256,
            xh, xl, 262144, b0 * 262144 + 0, 256,
            P, 1048576, 1024, 128, nullptr, nullptr, nullptr, 0, am + b0, nullptr);

        // K7: satT[n][c] = sum_m g[c][m] exp(P[n][m]-max)  (exp fused in staging, Z summed)
        mgemm<B16, EXPF, 2, true, false, false, false, false><<<dim3(16, 1, BCHUNK), 256, 0, stream>>>(
            g, nullptr, 131072, b0 * 131072, 1024,
            P, nullptr, 1048576, 0, 1024,
            satT + b0 * 131072, 131072, 128, 1024, nullptr, nullptr, nullptr, 0,
            am + b0, zs + b0);
    }
    invz_kernel<<<1, 64, 0, stream>>>(zs, invz);

    // K8: out0T[b*1024+n][oc] = invz[b] * omega_w[oc][:] . satT_unnorm + omega_b  (stats fused)
    mgemm<F32B, B16, 4, false, true, true, true, false><<<dim3(8, 2, 64), 256, 0, stream>>>(
        omega_w, nullptr, 0, 0, 128, satT, nullptr, 131072, 0, 128,
        out0T, 262144, 256, 128, omega_b, invz, r2, 256, nullptr, nullptr);
    finalize_stats<<<1, 256, 0, stream>>>(r2, 256, 256, omega_g, omega_be, sc2, sh2);

    final_kernel<<<dim3(16, 4, 64), 256, 0, stream>>>(x, out0T, sc2, sh2, out);
}

// Round 6
// 717.331 us; speedup vs baseline: 2.1368x; 1.0114x over previous
//
#include <hip/hip_runtime.h>
#include <cstdio>

// B=64, CIN=256, CP=128, N=1024. Stacked conv: 384 = theta|phi|gamma.
// GEMMs as A[M][k] x Bt[N][k], MFMA 16x16x32 bf16, split-bf16 (3 products) for
// conv1 + QK^T, plain bf16 for PV + omega. Softmax fused: QK^T epilogue does
// atomicMax(batch max); PV staging computes exp(S-max) (each P elem staged once)
// and accumulates Z; 1/Z folded into omega's per-batch epilogue scale.
// PIPE (reg-staged load->mfma->write pipeline) ONLY for non-split kernels:
// split staging regs held across MFMA spill past the VGPR budget (r5 evidence:
// VGPR 120 + 64MB extra WRITE_SIZE + 6x slowdown on K1/K4).

typedef __attribute__((ext_vector_type(4))) float f32x4;
typedef __attribute__((ext_vector_type(8))) short short8;
typedef __attribute__((ext_vector_type(4))) unsigned short u16x4;

static constexpr int BCHUNK = 16;

// ---- workspace layout (floats) ----
static constexpr long OFF_WST  = 0;          // 98304
static constexpr long OFF_VEC  = 98304;      // 1152: b|g|beta stacked
static constexpr long OFF_R1   = 99456;      // 768  (zeroed region start)
static constexpr long OFF_R2   = 100224;     // 512
static constexpr long OFF_ZS   = 100736;     // 64
static constexpr long OFF_AM   = 100800;     // 64 (uint)   (zeroed region: 1408)
static constexpr long OFF_SC1  = 100864;     // 384
static constexpr long OFF_SH1  = 101248;     // 384
static constexpr long OFF_SC2  = 101632;     // 256
static constexpr long OFF_SH2  = 101888;     // 256
static constexpr long OFF_INVZ = 102144;     // 64
static constexpr long OFF_A    = 131072;               // 16777216: xT hi/lo -> tpT hi/lo -> out0T f32
static constexpr long OFF_B    = OFF_A + 16777216;     // 25165824: YT f32 -> P f32 (chunk)
static constexpr long OFF_C    = OFF_B + 25165824;     // 4194304: g bf16 [64][128][1024]
static constexpr long OFF_D    = OFF_C + 4194304;      // 4194304: satT bf16 [64][1024][128]
static constexpr long WS_FLOATS = OFF_D + 4194304;     // ~202 MB

__device__ __forceinline__ unsigned short f2bf(float f) {
    union { float f; unsigned u; } x; x.f = f;
    unsigned r = x.u + 0x7FFF + ((x.u >> 16) & 1);
    return (unsigned short)(r >> 16);
}
__device__ __forceinline__ float bf2f(unsigned short h) {
    union { unsigned u; float f; } x; x.u = ((unsigned)h) << 16; return x.f;
}
// monotone float<->uint order encoding for atomicMax on signed floats
__device__ __forceinline__ unsigned fenc(float f) {
    unsigned u = __float_as_uint(f);
    return (u & 0x80000000u) ? ~u : (u | 0x80000000u);
}
__device__ __forceinline__ float fdec(unsigned e) {
    return __uint_as_float((e & 0x80000000u) ? (e & 0x7fffffffu) : ~e);
}

// ---------------- utility kernels ----------------
__global__ void zero_n(float* p, int n) {
    int i = blockIdx.x * 256 + threadIdx.x;
    if (i < n) p[i] = 0.f;
}

__global__ void invz_kernel(const float* zs, float* invz) {
    int i = threadIdx.x;
    if (i < 64) invz[i] = 1.0f / zs[i];
}

__global__ void stack_params(const float* tw, const float* tb, const float* tg, const float* tbe,
                             const float* pw, const float* pb, const float* pg, const float* pbe,
                             const float* gw, const float* gb, const float* gg, const float* gbe,
                             float* Wst, float* vecs) {
    int i = blockIdx.x * 256 + threadIdx.x;
    if (i < 98304) {
        int o = i >> 8, c = i & 255;
        float v = (o < 128) ? tw[o * 256 + c] : (o < 256) ? pw[(o - 128) * 256 + c]
                                                          : gw[(o - 256) * 256 + c];
        Wst[i] = v;
    }
    if (i < 384) {
        float b  = (i < 128) ? tb[i]  : (i < 256) ? pb[i - 128]  : gb[i - 256];
        float g  = (i < 128) ? tg[i]  : (i < 256) ? pg[i - 128]  : gg[i - 256];
        float be = (i < 128) ? tbe[i] : (i < 256) ? pbe[i - 128] : gbe[i - 256];
        vecs[i] = b; vecs[384 + i] = g; vecs[768 + i] = be;
    }
}

// x [64][256][1024] f32 -> xT [64][1024][256] bf16 hi/lo
__global__ __launch_bounds__(256) void transpose_x(const float* __restrict__ x,
                                                   unsigned short* __restrict__ xh,
                                                   unsigned short* __restrict__ xl) {
    __shared__ float t[64][68];
    const int b = blockIdx.z, c0 = blockIdx.y * 64, n0 = blockIdx.x * 64;
    const int tid = threadIdx.x;
#pragma unroll
    for (int p = 0; p < 4; ++p) {
        int i = tid + p * 256;
        int c = i >> 4, n4 = (i & 15) << 2;
        f32x4 v = *(const f32x4*)&x[((long)b * 256 + c0 + c) * 1024 + n0 + n4];
        *(f32x4*)&t[c][n4] = v;
    }
    __syncthreads();
#pragma unroll
    for (int p = 0; p < 4; ++p) {
        int i = tid + p * 256;
        int n = i >> 4, c4 = (i & 15) << 2;
        u16x4 h, l;
#pragma unroll
        for (int j = 0; j < 4; ++j) {
            float v = t[c4 + j][n];
            unsigned short hh = f2bf(v);
            h[j] = hh;
            l[j] = f2bf(v - bf2f(hh));
        }
        long o = ((long)b * 1024 + n0 + n) * 256 + c0 + c4;
        *(u16x4*)&xh[o] = h;
        *(u16x4*)&xl[o] = l;
    }
}

// ---------------- unified MFMA GEMM ----------------
// Src of a staged operand: F32S f32->split hi/lo; PRE pre-split bf16 hi/lo planes;
// F32B f32->bf16 (round); B16 plain bf16; EXPF f32 logits -> exp(v-max) bf16 + Z-sum.
enum Src { F32S, PRE, F32B, B16, EXPF };

template <Src S, int ROWS>
struct Stage {
    static constexpr int P = ROWS / 32;
    f32x4 raw[(S == F32S || S == F32B || S == EXPF) ? P : 1];
    u16x4 h[(S == PRE || S == B16) ? P : 1];
    u16x4 l[(S == PRE) ? P : 1];

    __device__ __forceinline__ void load(const void* hp, const void* lp, long base,
                                         int ld, int row0, int kt, int tid) {
#pragma unroll
        for (int p = 0; p < P; ++p) {
            int g = tid + p * 256;
            int row = g >> 3, kq = (g & 7) << 2;
            long gi = base + (long)(row0 + row) * ld + kt + kq;
            if constexpr (S == F32S || S == F32B || S == EXPF) {
                raw[p] = *(const f32x4*)((const float*)hp + gi);
            } else {
                h[p] = *(const u16x4*)((const unsigned short*)hp + gi);
                if constexpr (S == PRE) l[p] = *(const u16x4*)((const unsigned short*)lp + gi);
            }
        }
    }
    __device__ __forceinline__ void write(unsigned short* sh, unsigned short* sl, int tid,
                                          float mb, float& zacc) {
#pragma unroll
        for (int p = 0; p < P; ++p) {
            int g = tid + p * 256;
            int row = g >> 3, kq = (g & 7) << 2;
            u16x4 hh, ll;
            if constexpr (S == F32S) {
#pragma unroll
                for (int j = 0; j < 4; ++j) {
                    hh[j] = f2bf(raw[p][j]);
                    ll[j] = f2bf(raw[p][j] - bf2f(hh[j]));
                }
            } else if constexpr (S == EXPF) {
#pragma unroll
                for (int j = 0; j < 4; ++j) {
                    float e = exp2f((raw[p][j] - mb) * 1.4426950408889634f);
                    zacc += e;
                    hh[j] = f2bf(e);
                }
            } else if constexpr (S == F32B) {
#pragma unroll
                for (int j = 0; j < 4; ++j) hh[j] = f2bf(raw[p][j]);
            } else {
                hh = h[p];
                if constexpr (S == PRE) ll = l[p];
            }
            *(u16x4*)&sh[row * 40 + kq] = hh;
            if constexpr (S == F32S || S == PRE) *(u16x4*)&sl[row * 40 + kq] = ll;
        }
    }
};

// Block tile 128 x (NF*32), 4 waves as 2x2; wave tile 64 x (NF*16), frags 4xNF.
// Output Ct[N-col][M-row].
// PIPE=true : reg-staged pipeline load(k+1) -> mfma(k) -> sync -> write(k+1) -> sync
//             (only for small staging footprints — non-split).
// PIPE=false: direct staging load+write -> sync -> mfma -> sync (split kernels).
template <Src AS, Src BS, int NF, bool OUT_BF16, bool HAS_BIAS, bool HAS_SCALE,
          bool STATS, bool AMAX, bool PIPE>
__global__ __launch_bounds__(256) void mgemm(
    const void* __restrict__ Ah, const void* __restrict__ Al, long aBatch, long aOff, int lda,
    const void* __restrict__ Bh, const void* __restrict__ Bl, long bBatch, long bOff, int ldb,
    void* __restrict__ Cq, long cBatch, int ldc, int KTOT,
    const float* __restrict__ bias, const float* __restrict__ bscale,
    float* __restrict__ stats, int statStride,
    unsigned* __restrict__ amax, float* __restrict__ zsum) {
    constexpr bool SP = (AS == F32S || AS == PRE);
    constexpr int BROWS = NF * 32;
    constexpr int ASZ = 128 * 40, BSZ = BROWS * 40;
    __shared__ unsigned short lds[(SP ? 2 : 1) * (ASZ + BSZ)];
    unsigned short* Ash = lds;
    unsigned short* Bsh = lds + ASZ;
    unsigned short* Asl = SP ? (lds + ASZ + BSZ) : lds;
    unsigned short* Bsl = SP ? (lds + 2 * ASZ + BSZ) : lds;

    const int tid = threadIdx.x;
    const int wave = tid >> 6, lane = tid & 63;
    const int wm = wave >> 1, wn = wave & 1;
    const int lr = lane & 15, lg = lane >> 4;
    const int z = blockIdx.z;
    const int m0 = blockIdx.y * 128, n0 = blockIdx.x * BROWS;
    const long aB = aOff + (long)z * aBatch;
    const long bB = bOff + (long)z * bBatch;

    float mb = 0.f, zacc = 0.f;
    if constexpr (BS == EXPF) mb = fdec(amax[z]);

    f32x4 acc[4][NF];
#pragma unroll
    for (int i = 0; i < 4; ++i)
#pragma unroll
        for (int j = 0; j < NF; ++j) acc[i][j] = (f32x4){0.f, 0.f, 0.f, 0.f};

    Stage<AS, 128> sA;
    Stage<BS, BROWS> sB;

    auto mfma_phase = [&]() {
        short8 ah[4], al[4];
#pragma unroll
        for (int i = 0; i < 4; ++i) {
            ah[i] = *(const short8*)&Ash[(wm * 64 + i * 16 + lr) * 40 + lg * 8];
            if constexpr (SP) al[i] = *(const short8*)&Asl[(wm * 64 + i * 16 + lr) * 40 + lg * 8];
        }
#pragma unroll
        for (int ni = 0; ni < NF; ++ni) {
            const int brow = (wn * NF * 16 + ni * 16 + lr) * 40 + lg * 8;
            short8 bh = *(const short8*)&Bsh[brow];
#pragma unroll
            for (int mi = 0; mi < 4; ++mi)
                acc[mi][ni] = __builtin_amdgcn_mfma_f32_16x16x32_bf16(ah[mi], bh,
                                                                     acc[mi][ni], 0, 0, 0);
            if constexpr (SP) {
                short8 bl = *(const short8*)&Bsl[brow];
#pragma unroll
                for (int mi = 0; mi < 4; ++mi) {
                    acc[mi][ni] = __builtin_amdgcn_mfma_f32_16x16x32_bf16(ah[mi], bl,
                                                                         acc[mi][ni], 0, 0, 0);
                    acc[mi][ni] = __builtin_amdgcn_mfma_f32_16x16x32_bf16(al[mi], bh,
                                                                         acc[mi][ni], 0, 0, 0);
                }
            }
        }
    };

    if constexpr (PIPE) {
        sA.load(Ah, Al, aB, lda, m0, 0, tid);
        sB.load(Bh, Bl, bB, ldb, n0, 0, tid);
        sA.write(Ash, Asl, tid, mb, zacc);
        sB.write(Bsh, Bsl, tid, mb, zacc);
        __syncthreads();
        for (int kt = 32; kt < KTOT + 32; kt += 32) {
            const bool more = kt < KTOT;
            if (more) {
                sA.load(Ah, Al, aB, lda, m0, kt, tid);
                sB.load(Bh, Bl, bB, ldb, n0, kt, tid);
            }
            mfma_phase();
            __syncthreads();
            if (more) {
                sA.write(Ash, Asl, tid, mb, zacc);
                sB.write(Bsh, Bsl, tid, mb, zacc);
                __syncthreads();
            }
        }
    } else {
        for (int kt = 0; kt < KTOT; kt += 32) {
            sA.load(Ah, Al, aB, lda, m0, kt, tid);
            sA.write(Ash, Asl, tid, mb, zacc);
            sB.load(Bh, Bl, bB, ldb, n0, kt, tid);
            sB.write(Bsh, Bsl, tid, mb, zacc);
            __syncthreads();
            mfma_phase();
            __syncthreads();
        }
    }

    // Z accumulation (EXPF): block-reduce zacc, one atomic per block
    if constexpr (BS == EXPF) {
        float* red = (float*)lds;
        red[tid] = zacc;
        __syncthreads();
        for (int o = 128; o > 0; o >>= 1) {
            if (tid < o) red[tid] += red[tid + o];
            __syncthreads();
        }
        if (tid == 0) atomicAdd(&zsum[z], red[0]);
    }

    const float sc = HAS_SCALE ? bscale[z] : 1.0f;
    float lmax = -3.4e38f;
#pragma unroll
    for (int mi = 0; mi < 4; ++mi) {
        const int mrow = m0 + wm * 64 + mi * 16 + lg * 4;
        f32x4 bi = (f32x4){0.f, 0.f, 0.f, 0.f};
        if constexpr (HAS_BIAS) bi = *(const f32x4*)&bias[mrow];
        f32x4 s = (f32x4){0.f, 0.f, 0.f, 0.f}, s2 = s;
#pragma unroll
        for (int ni = 0; ni < NF; ++ni) {
            const int col = n0 + wn * NF * 16 + ni * 16 + lr;
            f32x4 v = acc[mi][ni] * sc + bi;
            if constexpr (STATS) { s += v; s2 += v * v; }
            if constexpr (AMAX) {
#pragma unroll
                for (int j = 0; j < 4; ++j) lmax = fmaxf(lmax, v[j]);
            }
            long ci = (long)z * cBatch + (long)col * ldc + mrow;
            if constexpr (OUT_BF16) {
                u16x4 o;
#pragma unroll
                for (int j = 0; j < 4; ++j) o[j] = f2bf(v[j]);
                *(u16x4*)((unsigned short*)Cq + ci) = o;
            } else {
                *(f32x4*)((float*)Cq + ci) = v;
            }
        }
        if constexpr (STATS) {
#pragma unroll
            for (int m = 1; m < 16; m <<= 1) {
#pragma unroll
                for (int r = 0; r < 4; ++r) {
                    s[r] += __shfl_xor(s[r], m);
                    s2[r] += __shfl_xor(s2[r], m);
                }
            }
            if (lr == 0) {
#pragma unroll
                for (int r = 0; r < 4; ++r) {
                    atomicAdd(&stats[mrow + r], s[r]);
                    atomicAdd(&stats[statStride + mrow + r], s2[r]);
                }
            }
        }
    }
    if constexpr (AMAX) {
#pragma unroll
        for (int o = 1; o < 64; o <<= 1) lmax = fmaxf(lmax, __shfl_xor(lmax, o));
        if (lane == 0) atomicMax(&amax[z], fenc(lmax));
    }
}

// raw sums -> per-channel scale/shift
__global__ void finalize_stats(const float* __restrict__ raw, int n, int stride,
                               const float* __restrict__ g, const float* __restrict__ beta,
                               float* __restrict__ osc, float* __restrict__ osh) {
    int ch = blockIdx.x * 256 + threadIdx.x;
    if (ch < n) {
        double mean = (double)raw[ch] / 65536.0;
        double var = (double)raw[stride + ch] / 65536.0 - mean * mean;
        double s = (double)g[ch] / sqrt(var + 1e-5);
        osc[ch] = (float)s;
        osh[ch] = (float)((double)beta[ch] - mean * s);
    }
}

// normalize theta/phi cols (0..255) of YT -> split bf16 planes tpT [row][256]
__global__ __launch_bounds__(256) void norm_tp(const float* __restrict__ YT,
                                               const float* __restrict__ sc,
                                               const float* __restrict__ sh,
                                               unsigned short* __restrict__ th,
                                               unsigned short* __restrict__ tl) {
    const long total = 64L * 1024 * 64;  // f4 groups
    for (long idx = (long)blockIdx.x * 256 + threadIdx.x; idx < total;
         idx += (long)gridDim.x * 256) {
        long row = idx >> 6;
        int cg = (int)(idx & 63) << 2;
        f32x4 v = *(const f32x4*)&YT[row * 384 + cg];
        f32x4 scv = *(const f32x4*)&sc[cg];
        f32x4 shv = *(const f32x4*)&sh[cg];
        v = v * scv + shv;
        u16x4 h, l;
#pragma unroll
        for (int j = 0; j < 4; ++j) {
            unsigned short hh = f2bf(v[j]);
            h[j] = hh;
            l[j] = f2bf(v[j] - bf2f(hh));
        }
        *(u16x4*)&th[row * 256 + cg] = h;
        *(u16x4*)&tl[row * 256 + cg] = l;
    }
}

// normalize gamma cols (256..383) of YT, transpose -> g bf16 [64][128][1024]
__global__ __launch_bounds__(256) void norm_g(const float* __restrict__ YT,
                                              const float* __restrict__ sc,
                                              const float* __restrict__ sh,
                                              unsigned short* __restrict__ g) {
    __shared__ float t[64][68];
    const int b = blockIdx.z, c0 = blockIdx.y * 64, n0 = blockIdx.x * 64;
    const int tid = threadIdx.x;
#pragma unroll
    for (int p = 0; p < 4; ++p) {
        int i = tid + p * 256;
        int n = i >> 4, c4 = (i & 15) << 2;
        f32x4 v = *(const f32x4*)&YT[((long)b * 1024 + n0 + n) * 384 + 256 + c0 + c4];
        f32x4 scv = *(const f32x4*)&sc[256 + c0 + c4];
        f32x4 shv = *(const f32x4*)&sh[256 + c0 + c4];
        v = v * scv + shv;
        *(f32x4*)&t[n][c4] = v;
    }
    __syncthreads();
#pragma unroll
    for (int p = 0; p < 4; ++p) {
        int i = tid + p * 256;
        int c = i >> 4, n4 = (i & 15) << 2;
        u16x4 o;
#pragma unroll
        for (int j = 0; j < 4; ++j) o[j] = f2bf(t[n4 + j][c]);
        *(u16x4*)&g[((long)b * 128 + c0 + c) * 1024 + n0 + n4] = o;
    }
}

// out[b][oc][n] = x + sc2[oc]*out0T[b][n][oc] + sh2[oc]  (LDS tile transpose)
__global__ __launch_bounds__(256) void final_kernel(const float* __restrict__ x,
                                                    const float* __restrict__ out0T,
                                                    const float* __restrict__ sc,
                                                    const float* __restrict__ sh,
                                                    float* __restrict__ out) {
    __shared__ float t[64][68];
    const int b = blockIdx.z, oc0 = blockIdx.y * 64, n0 = blockIdx.x * 64;
    const int tid = threadIdx.x;
#pragma unroll
    for (int p = 0; p < 4; ++p) {
        int i = tid + p * 256;
        int n = i >> 4, c4 = (i & 15) << 2;
        f32x4 v = *(const f32x4*)&out0T[((long)b * 1024 + n0 + n) * 256 + oc0 + c4];
        *(f32x4*)&t[n][c4] = v;
    }
    __syncthreads();
#pragma unroll
    for (int p = 0; p < 4; ++p) {
        int i = tid + p * 256;
        int oc = i >> 4, n4 = (i & 15) << 2;
        const float scv = sc[oc0 + oc], shv = sh[oc0 + oc];
        long o = ((long)b * 256 + oc0 + oc) * 1024 + n0 + n4;
        f32x4 xv = *(const f32x4*)&x[o];
        f32x4 v;
#pragma unroll
        for (int j = 0; j < 4; ++j) v[j] = xv[j] + t[n4 + j][oc] * scv + shv;
        *(f32x4*)&out[o] = v;
    }
}

extern "C" void kernel_launch(void* const* d_in, const int* in_sizes, int n_in,
                              void* d_out, int out_size, void* d_ws, size_t ws_size,
                              hipStream_t stream) {
    const float* x        = (const float*)d_in[0];
    const float* theta_w  = (const float*)d_in[1];
    const float* theta_b  = (const float*)d_in[2];
    const float* theta_g  = (const float*)d_in[3];
    const float* theta_be = (const float*)d_in[4];
    const float* phi_w    = (const float*)d_in[5];
    const float* phi_b    = (const float*)d_in[6];
    const float* phi_g    = (const float*)d_in[7];
    const float* phi_be   = (const float*)d_in[8];
    const float* gamma_w  = (const float*)d_in[9];
    const float* gamma_b  = (const float*)d_in[10];
    const float* gamma_g  = (const float*)d_in[11];
    const float* gamma_be = (const float*)d_in[12];
    const float* omega_w  = (const float*)d_in[13];
    const float* omega_b  = (const float*)d_in[14];
    const float* omega_g  = (const float*)d_in[15];
    const float* omega_be = (const float*)d_in[16];
    float* out = (float*)d_out;

    const size_t need = (size_t)WS_FLOATS * 4;
    if (ws_size < need) {
        fprintf(stderr, "kernel_launch: ws_size %zu < needed %zu\n", ws_size, need);
        return;
    }
    float* ws = (float*)d_ws;
    float* Wst  = ws + OFF_WST;
    float* vecs = ws + OFF_VEC;
    float* r1   = ws + OFF_R1;
    float* r2   = ws + OFF_R2;
    float* zs   = ws + OFF_ZS;
    unsigned* am = (unsigned*)(ws + OFF_AM);
    float* sc1  = ws + OFF_SC1;
    float* sh1  = ws + OFF_SH1;
    float* sc2  = ws + OFF_SC2;
    float* sh2  = ws + OFF_SH2;
    float* invz = ws + OFF_INVZ;
    unsigned short* xh  = (unsigned short*)(ws + OFF_A);            // also tpT hi
    unsigned short* xl  = (unsigned short*)(ws + OFF_A + 8388608);  // also tpT lo
    float* out0T        = ws + OFF_A;                               // overlays xT/tpT
    float* YT           = ws + OFF_B;                               // [64*1024][384]
    float* P            = ws + OFF_B;                               // [16][1024][1024] overlays YT
    unsigned short* g   = (unsigned short*)(ws + OFF_C);            // [64][128][1024]
    unsigned short* satT= (unsigned short*)(ws + OFF_D);            // [64][1024][128]

    // zero r1|r2|zsum|amax (contiguous 1408 floats)
    zero_n<<<6, 256, 0, stream>>>(r1, 1408);
    stack_params<<<384, 256, 0, stream>>>(theta_w, theta_b, theta_g, theta_be,
                                          phi_w, phi_b, phi_g, phi_be,
                                          gamma_w, gamma_b, gamma_g, gamma_be, Wst, vecs);
    transpose_x<<<dim3(16, 4, 64), 256, 0, stream>>>(x, xh, xl);

    // K1: YT[b*1024+n][oc] = Wst[oc][:] . x[b][:][n] + bias  (split, stats fused, direct stage)
    mgemm<F32S, PRE, 4, false, true, false, true, false, false><<<dim3(8, 3, 64), 256, 0, stream>>>(
        Wst, nullptr, 0, 0, 256, xh, xl, 262144, 0, 256,
        YT, 393216, 384, 256, vecs, nullptr, r1, 384, nullptr, nullptr);
    finalize_stats<<<2, 256, 0, stream>>>(r1, 384, 384, vecs + 384, vecs + 768, sc1, sh1);

    norm_tp<<<4096, 256, 0, stream>>>(YT, sc1, sh1, xh, xl);  // tpT planes (overwrite xT)
    norm_g<<<dim3(16, 2, 64), 256, 0, stream>>>(YT, sc1, sh1, g);

    for (int c = 0; c < 4; ++c) {
        const long b0 = (long)c * BCHUNK;
        // K4: P[n][m] = logits, epilogue atomicMax -> am[b]  (split, direct stage)
        mgemm<PRE, PRE, 4, false, false, false, false, true, false><<<dim3(8, 8, BCHUNK), 256, 0, stream>>>(
            xh, xl, 262144, b0 * 262144 + 128, 256,
            xh, xl, 262144, b0 * 262144 + 0, 256,
            P, 1048576, 1024, 128, nullptr, nullptr, nullptr, 0, am + b0, nullptr);

        // K7: satT[n][c] = sum_m g[c][m] exp(P[n][m]-max)  (exp fused in staging, Z summed, piped)
        mgemm<B16, EXPF, 2, true, false, false, false, false, true><<<dim3(16, 1, BCHUNK), 256, 0, stream>>>(
            g, nullptr, 131072, b0 * 131072, 1024,
            P, nullptr, 1048576, 0, 1024,
            satT + b0 * 131072, 131072, 128, 1024, nullptr, nullptr, nullptr, 0,
            am + b0, zs + b0);
    }
    invz_kernel<<<1, 64, 0, stream>>>(zs, invz);

    // K8: out0T[b*1024+n][oc] = invz[b] * omega_w[oc][:] . satT_unnorm + omega_b  (stats fused, piped)
    mgemm<F32B, B16, 4, false, true, true, true, false, true><<<dim3(8, 2, 64), 256, 0, stream>>>(
        omega_w, nullptr, 0, 0, 128, satT, nullptr, 131072, 0, 128,
        out0T, 262144, 256, 128, omega_b, invz, r2, 256, nullptr, nullptr);
    finalize_stats<<<1, 256, 0, stream>>>(r2, 256, 256, omega_g, omega_be, sc2, sh2);

    final_kernel<<<dim3(16, 4, 64), 256, 0, stream>>>(x, out0T, sc2, sh2, out);
}